// Round 8
// baseline (420.639 us; speedup 1.0000x reference)
//
#include <hip/hip_runtime.h>
#include <hip/hip_cooperative_groups.h>
#include <math.h>

#define BATCH 16384
#define LBL   512
#define HID   768
#define TR    128

namespace cg = cooperative_groups;

typedef unsigned long long u64;
typedef unsigned short ushort_t;
typedef __attribute__((ext_vector_type(8))) short short8;
typedef __attribute__((ext_vector_type(4))) float f32x4;

__device__ __forceinline__ ushort_t f2bf(float f){
  unsigned u = __builtin_bit_cast(unsigned, f);
  u += 0x7FFFu + ((u >> 16) & 1u);
  return (ushort_t)(u >> 16);
}
__device__ __forceinline__ float bf2f(ushort_t h){
  unsigned u = ((unsigned)h) << 16;
  return __builtin_bit_cast(float, u);
}
__device__ __forceinline__ float softplusf(float x){
  return fmaxf(x, 0.0f) + log1pf(expf(-fabsf(x)));
}
__device__ __forceinline__ void gload_lds16(const void* g, void* l){
  __builtin_amdgcn_global_load_lds((const __attribute__((address_space(1))) void*)g,
                                   (__attribute__((address_space(3))) void*)l, 16, 0, 0);
}

// ===================================================================
// Fused cooperative kernel: 512 blocks x 256 thr, 32 samples/block.
// LDS: uni 43008 + bits 2560 + invs/perm 256 = ~45.8KB -> 3 blocks/CU by LDS;
// launch_bounds(256,2) -> needs only 2/CU for the 512-block coop grid.
// ===================================================================

// 32-row x 128-col tile GEMM, K=768. B pre-swizzled: chunk kc = contiguous 16KB at
// elem kc*8192, element (n,k) at ((k>>3)<<10)+(n<<3)+(k&7). A fp32 rows -> bf16 LDS.
// As_: [2][32][80] ushort (10240B); Bs_: [2][8192] ushort (32768B).
__device__ __forceinline__ void gemm768_32(const float* ap, const ushort_t* Bsw,
                                           ushort_t* As_, ushort_t* Bs_,
                                           int tid, int wave, int m, int q,
                                           f32x4 acc[2][2]){
  int arow = tid >> 3, ak = (tid & 7) * 8;
  (void)arow; (void)ak;
  float4 ra0 = *(const float4*)ap;
  float4 ra1 = *(const float4*)(ap + 4);
  {
    const char* gb = (const char*)Bsw;
    char* lb = (char*)Bs_;
    #pragma unroll
    for (int p = 0; p < 4; p++)
      gload_lds16(gb + p*4096 + tid*16, lb + p*4096 + tid*16);
  }
  #pragma unroll
  for (int rt = 0; rt < 2; rt++)
    #pragma unroll
    for (int ct = 0; ct < 2; ct++)
      acc[rt][ct] = (f32x4){0.f,0.f,0.f,0.f};

  for (int c = 0; c < 12; c++){
    int buf = c & 1;
    short8 av;
    av[0] = (short)f2bf(ra0.x); av[1] = (short)f2bf(ra0.y);
    av[2] = (short)f2bf(ra0.z); av[3] = (short)f2bf(ra0.w);
    av[4] = (short)f2bf(ra1.x); av[5] = (short)f2bf(ra1.y);
    av[6] = (short)f2bf(ra1.z); av[7] = (short)f2bf(ra1.w);
    *(short8*)(As_ + (size_t)(buf*32 + (tid >> 3))*80 + (tid & 7)*8) = av;
    __syncthreads();
    if (c < 11){
      ra0 = *(const float4*)(ap + (c+1)*64);
      ra1 = *(const float4*)(ap + (c+1)*64 + 4);
      const char* gb = (const char*)Bsw + (size_t)(c+1)*16384;
      char* lb = (char*)(Bs_ + (buf^1)*8192);
      #pragma unroll
      for (int p = 0; p < 4; p++)
        gload_lds16(gb + p*4096 + tid*16, lb + p*4096 + tid*16);
    }
    #pragma unroll
    for (int kcc = 0; kcc < 2; kcc++){
      short8 bfr[2];
      #pragma unroll
      for (int ct = 0; ct < 2; ct++)
        bfr[ct] = *(const short8*)(Bs_ + buf*8192 + (kcc*4 + q)*1024 + (wave*32 + ct*16 + m)*8);
      #pragma unroll
      for (int rt = 0; rt < 2; rt++){
        short8 a = *(const short8*)(As_ + (size_t)(buf*32 + rt*16 + m)*80 + kcc*32 + q*8);
        #pragma unroll
        for (int ct = 0; ct < 2; ct++)
          acc[rt][ct] = __builtin_amdgcn_mfma_f32_16x16x32_bf16(a, bfr[ct], acc[rt][ct], 0, 0, 0);
      }
    }
  }
}

__global__ __launch_bounds__(256, 2) void kfused(
    const float* __restrict__ W0, const float* __restrict__ Wt, const float* __restrict__ Wl,
    const float* __restrict__ bt, const float* __restrict__ bl, const float* __restrict__ b0,
    const float* __restrict__ W1, const float* __restrict__ T,  const float* __restrict__ labe,
    const int* __restrict__ tgt,  const int* __restrict__ perm,
    const float* __restrict__ b1, const float* __restrict__ W2, const float* __restrict__ b2,
    ushort_t* __restrict__ Msw, ushort_t* __restrict__ Qsw, ushort_t* __restrict__ W1B,
    float* __restrict__ KV, ushort_t* __restrict__ Gt, ushort_t* __restrict__ U,
    float* __restrict__ out){
  __shared__ __align__(16) char uni[43008];
  __shared__ __align__(16) u64 bitsS[32*10];         // 80B pitch per row
  __shared__ float invs[32];
  __shared__ int   permS[32];

  cg::grid_group grid = cg::this_grid();
  int bi = blockIdx.x, tid = threadIdx.x;
  int lane = tid & 63, wave = tid >> 6;
  int m = lane & 15, q = lane >> 4;
  int r0 = bi * 32;
  int arow = tid >> 3, ak = (tid & 7) * 8;

  // ================= Phase A: bitpack own 32 rows + weight prep =================
  if (tid < 32) permS[tid] = perm[r0 + tid];
  #pragma unroll
  for (int rr = 0; rr < 8; rr++){
    int row = wave*8 + rr;
    const int* rp = tgt + (size_t)(r0 + row)*LBL;
    int v[8];
    #pragma unroll
    for (int c = 0; c < 8; c++) v[c] = rp[c*64 + lane];
    int cnt = 0;
    #pragma unroll
    for (int c = 0; c < 8; c++){
      u64 mm = __ballot(v[c] != 0);
      if (lane == 0){ bitsS[row*10 + c] = mm; cnt += __popcll(mm); }
    }
    if (lane == 0) invs[row] = 1.0f / (float)(cnt < 1 ? 1 : cnt);
  }

  if (bi < 256){
    int i = bi & 127;
    int isQ = bi >> 7;
    const float* src = isQ ? Wl : Wt;
    ushort_t* dst = isQ ? Qsw : Msw;
    float* sw = (float*)uni;
    if (tid < TR) sw[tid] = W0[(size_t)i*256 + isQ*128 + tid];
    if (!isQ && tid < 128) W1B[i*128 + tid] = f2bf(W1[i*128 + tid]);
    __syncthreads();
    int c = tid;
    float a0 = 0.f, a1 = 0.f, a2 = 0.f;
    #pragma unroll 8
    for (int a = 0; a < 128; a++){
      float w = sw[a];
      const float* r = src + (size_t)a*HID;
      a0 = fmaf(w, r[c], a0);
      a1 = fmaf(w, r[c+256], a1);
      a2 = fmaf(w, r[c+512], a2);
    }
    int c7 = c & 7;
    dst[(((c      )>>3)<<10) + (i<<3) + c7] = f2bf(a0);
    dst[(((c + 256)>>3)<<10) + (i<<3) + c7] = f2bf(a1);
    dst[(((c + 512)>>3)<<10) + (i<<3) + c7] = f2bf(a2);
  } else if (bi == 256){
    if (tid < TR){
      float s = b0[tid];
      const float* r = W0 + (size_t)tid*256;
      for (int a = 0; a < 128; a++) s = fmaf(r[a], bt[a], s);
      for (int a = 0; a < 128; a++) s = fmaf(r[128+a], bl[a], s);
      KV[tid] = s;
    }
    if (tid == 0) out[0] = 0.f;
  }
  __threadfence();
  grid.sync();

  // ================= Phase B: U tile (kept in regs) + G for blocks 0..15 =================
  ushort_t* Bs_ = (ushort_t*)uni;            // [2][8192]  32768B
  ushort_t* As_ = (ushort_t*)(uni + 32768);  // [2][32][80] 10240B

  f32x4 accU[2][2];
  gemm768_32(T + (size_t)(r0 + arow)*HID + ak, Msw, As_, Bs_, tid, wave, m, q, accU);

  float upf[2][2][4];
  #pragma unroll
  for (int rt = 0; rt < 2; rt++)
    #pragma unroll
    for (int ct = 0; ct < 2; ct++){
      int col = wave*32 + ct*16 + m;
      float kv = KV[col];
      #pragma unroll
      for (int r = 0; r < 4; r++){
        upf[rt][ct][r] = accU[rt][ct][r] + kv;
        U[(size_t)(r0 + rt*16 + q*4 + r)*TR + col] = f2bf(upf[rt][ct][r]);
      }
    }

  if (bi < 16){
    int l0 = bi * 32;
    f32x4 accG[2][2];
    __syncthreads();
    gemm768_32(labe + (size_t)(l0 + arow)*HID + ak, Qsw, As_, Bs_, tid, wave, m, q, accG);
    __syncthreads();
    ushort_t (*GTs)[40] = (ushort_t(*)[40])uni;   // [128][40] = 10240B
    #pragma unroll
    for (int rt = 0; rt < 2; rt++)
      #pragma unroll
      for (int ct = 0; ct < 2; ct++){
        int col = wave*32 + ct*16 + m;
        #pragma unroll
        for (int r = 0; r < 4; r++)
          GTs[col][rt*16 + q*4 + r] = f2bf(accG[rt][ct][r]);
      }
    __syncthreads();
    int gi = tid >> 1, half = tid & 1;
    ushort_t* dstp = Gt + (size_t)gi*LBL + l0 + half*16;
    *(short8*)(dstp)     = *(const short8*)&GTs[gi][half*16];
    *(short8*)(dstp + 8) = *(const short8*)&GTs[gi][half*16 + 8];
  }
  __threadfence();
  grid.sync();

  // ================= Phase C: V + h0(both) + h1(both) + score =================
  ushort_t (*h0s)[136] = (ushort_t(*)[136])uni;   // [64][136] 17408B: 0-31 pos, 32-63 neg
  float* sred = (float*)(uni + 17408);            // [4 wave][4 rt2][16][17] 17408B

  // hoist neg-branch U gather (latency covered by V-GEMM)
  float un[2][2][4];
  #pragma unroll
  for (int rt = 0; rt < 2; rt++)
    #pragma unroll
    for (int ct = 0; ct < 2; ct++){
      int col = wave*32 + ct*16 + m;
      #pragma unroll
      for (int r = 0; r < 4; r++)
        un[rt][ct][r] = bf2f(U[(size_t)permS[rt*16 + q*4 + r]*TR + col]);
    }

  // V = mask @ G (K=512), Gt prefetch 1-deep
  const unsigned char* bits_b = (const unsigned char*)bitsS;
  f32x4 accV[2][2] = {{{0,0,0,0},{0,0,0,0}},{{0,0,0,0},{0,0,0,0}}};
  const ushort_t* gp[2];
  #pragma unroll
  for (int ct = 0; ct < 2; ct++)
    gp[ct] = Gt + (size_t)(wave*32 + ct*16 + m)*LBL + q*8;
  short8 bcur[2], bnext[2];
  #pragma unroll
  for (int ct = 0; ct < 2; ct++) bcur[ct] = *(const short8*)(gp[ct]);
  for (int c = 0; c < 16; c++){
    if (c < 15){
      #pragma unroll
      for (int ct = 0; ct < 2; ct++) bnext[ct] = *(const short8*)(gp[ct] + (c+1)*32);
    }
    #pragma unroll
    for (int rt = 0; rt < 2; rt++){
      unsigned bb = bits_b[(rt*16 + m)*80 + c*4 + q];
      short8 a;
      #pragma unroll
      for (int j = 0; j < 8; j++) a[j] = (short)(((bb >> j) & 1u) ? 0x3F80 : 0);
      #pragma unroll
      for (int ct = 0; ct < 2; ct++)
        accV[rt][ct] = __builtin_amdgcn_mfma_f32_16x16x32_bf16(a, bcur[ct], accV[rt][ct], 0, 0, 0);
    }
    #pragma unroll
    for (int ct = 0; ct < 2; ct++) bcur[ct] = bnext[ct];
  }

  __syncthreads();   // uni transitions to h0s
  #pragma unroll
  for (int rt = 0; rt < 2; rt++)
    #pragma unroll
    for (int ct = 0; ct < 2; ct++){
      int col = wave*32 + ct*16 + m;
      #pragma unroll
      for (int r = 0; r < 4; r++){
        int rowl = rt*16 + q*4 + r;
        float v = accV[rt][ct][r] * invs[rowl];
        h0s[rowl][col]      = f2bf(fmaxf(upf[rt][ct][r] + v, 0.f));
        h0s[32 + rowl][col] = f2bf(fmaxf(un[rt][ct][r]  + v, 0.f));
      }
    }
  __syncthreads();

  float w2c[2], b1c[2];
  #pragma unroll
  for (int ct = 0; ct < 2; ct++){
    int col = wave*32 + ct*16 + m;
    w2c[ct] = W2[col];
    b1c[ct] = b1[col];
  }
  float b2v = b2[0];

  #pragma unroll
  for (int rt2 = 0; rt2 < 4; rt2++){
    f32x4 accH[2] = {{0,0,0,0},{0,0,0,0}};
    #pragma unroll
    for (int kc = 0; kc < 4; kc++){
      short8 a = *(const short8*)&h0s[rt2*16 + m][kc*32 + q*8];
      #pragma unroll
      for (int ct = 0; ct < 2; ct++){
        short8 b = *(const short8*)(W1B + (size_t)(wave*32 + ct*16 + m)*TR + kc*32 + q*8);
        accH[ct] = __builtin_amdgcn_mfma_f32_16x16x32_bf16(a, b, accH[ct], 0, 0, 0);
      }
    }
    #pragma unroll
    for (int r = 0; r < 4; r++){
      float sp = 0.f;
      #pragma unroll
      for (int ct = 0; ct < 2; ct++)
        sp = fmaf(w2c[ct], fmaxf(accH[ct][r] + b1c[ct], 0.f), sp);
      sred[((wave*4 + rt2)*16 + q*4 + r)*17 + m] = sp;
    }
  }
  __syncthreads();

  if (tid < 64){
    int rt2 = tid >> 4, row = tid & 15;
    float s = b2v;
    #pragma unroll
    for (int wx = 0; wx < 4; wx++)
      #pragma unroll
      for (int n = 0; n < 16; n++) s += sred[((wx*4 + rt2)*16 + row)*17 + n];
    float val = (rt2 < 2) ? softplusf(-s) : softplusf(s);   // rt2 0,1 = pos branch
    #pragma unroll
    for (int off = 32; off > 0; off >>= 1) val += __shfl_down(val, off);
    if (tid == 0) atomicAdd(out, val * (1.0f / (float)BATCH));
  }
}

// ===================================================================
// Fallback pipeline (round-6 proven kernels, verbatim)
// ===================================================================
__global__ __launch_bounds__(256) void k1(
    const float* __restrict__ W0, const float* __restrict__ Wt, const float* __restrict__ Wl,
    const float* __restrict__ bt, const float* __restrict__ bl, const float* __restrict__ b0,
    const float* __restrict__ W1,
    ushort_t* __restrict__ Msw, ushort_t* __restrict__ Qsw, ushort_t* __restrict__ W1B,
    float* __restrict__ KV, float* __restrict__ out){
  __shared__ float sw[TR];
  int bi = blockIdx.x, t = threadIdx.x;
  if (bi < 256){
    int i = bi & 127;
    int isQ = bi >> 7;
    const float* src = isQ ? Wl : Wt;
    ushort_t* dst = isQ ? Qsw : Msw;
    if (t < TR) sw[t] = W0[(size_t)i*256 + isQ*128 + t];
    if (!isQ && t < 128) W1B[i*128 + t] = f2bf(W1[i*128 + t]);
    __syncthreads();
    int c = t;
    float a0 = 0.f, a1 = 0.f, a2 = 0.f;
    #pragma unroll 8
    for (int a = 0; a < 128; a++){
      float w = sw[a];
      const float* r = src + (size_t)a*HID;
      a0 = fmaf(w, r[c], a0);
      a1 = fmaf(w, r[c+256], a1);
      a2 = fmaf(w, r[c+512], a2);
    }
    int c7 = c & 7;
    dst[(((c      )>>3)<<10) + (i<<3) + c7] = f2bf(a0);
    dst[(((c + 256)>>3)<<10) + (i<<3) + c7] = f2bf(a1);
    dst[(((c + 512)>>3)<<10) + (i<<3) + c7] = f2bf(a2);
  } else {
    if (t < TR){
      float s = b0[t];
      const float* r = W0 + (size_t)t*256;
      for (int a = 0; a < 128; a++) s = fmaf(r[a], bt[a], s);
      for (int a = 0; a < 128; a++) s = fmaf(r[128+a], bl[a], s);
      KV[t] = s;
    }
    if (t == 0) out[0] = 0.f;
  }
}

__global__ __launch_bounds__(256) void k2(
    const float* __restrict__ labe, const ushort_t* __restrict__ Qsw,
    const float* __restrict__ T,    const ushort_t* __restrict__ Msw,
    const float* __restrict__ KV,
    ushort_t* __restrict__ Gt, ushort_t* __restrict__ U){
  __shared__ __align__(16) ushort_t Bs[2][8192];
  __shared__ __align__(16) ushort_t As[2][16][72];
  int bi = blockIdx.x, tid = threadIdx.x;
  int lane = tid & 63, wave = tid >> 6;
  int m = lane & 15, q = lane >> 4;
  int arow = tid >> 4, a4 = (tid & 15) * 4;

  if (bi < 32){
    int l0 = bi * 16;
    const float* ap = labe + (size_t)(l0 + arow)*HID + a4;
    float4 ra = *(const float4*)ap;
    {
      const char* gb = (const char*)Qsw;
      char* lb = (char*)&Bs[0][0];
      #pragma unroll
      for (int p = 0; p < 4; p++)
        gload_lds16(gb + p*4096 + tid*16, lb + p*4096 + tid*16);
    }
    f32x4 acc[2] = {{0,0,0,0},{0,0,0,0}};
    for (int c = 0; c < 12; c++){
      int buf = c & 1;
      ushort_t* ad = &As[buf][arow][a4];
      ad[0]=f2bf(ra.x); ad[1]=f2bf(ra.y); ad[2]=f2bf(ra.z); ad[3]=f2bf(ra.w);
      __syncthreads();
      if (c < 11){
        ra = *(const float4*)(ap + (c+1)*64);
        const char* gb = (const char*)Qsw + (size_t)(c+1)*16384;
        char* lb = (char*)&Bs[buf^1][0];
        #pragma unroll
        for (int p = 0; p < 4; p++)
          gload_lds16(gb + p*4096 + tid*16, lb + p*4096 + tid*16);
      }
      #pragma unroll
      for (int kcc = 0; kcc < 2; kcc++){
        short8 a = *(const short8*)&As[buf][m][kcc*32 + q*8];
        #pragma unroll
        for (int ct = 0; ct < 2; ct++){
          int col = wave*32 + ct*16 + m;
          short8 b = *(const short8*)&Bs[buf][(kcc*4 + q)*1024 + col*8];
          acc[ct] = __builtin_amdgcn_mfma_f32_16x16x32_bf16(a, b, acc[ct], 0, 0, 0);
        }
      }
    }
    __syncthreads();
    ushort_t (*GTs)[24] = (ushort_t(*)[24])&Bs[0][0];
    #pragma unroll
    for (int ct = 0; ct < 2; ct++){
      int col = wave*32 + ct*16 + m;
      #pragma unroll
      for (int r = 0; r < 4; r++)
        GTs[col][q*4 + r] = f2bf(acc[ct][r]);
    }
    __syncthreads();
    int gi = tid >> 1, loff = (tid & 1) * 8;
    *(short8*)(Gt + (size_t)gi*LBL + l0 + loff) = *(const short8*)&GTs[gi][loff];
  } else {
    int r0 = (bi - 32) * 16;
    const float* ap = T + (size_t)(r0 + arow)*HID + a4;
    float4 ra = *(const float4*)ap;
    {
      const char* gb = (const char*)Msw;
      char* lb = (char*)&Bs[0][0];
      #pragma unroll
      for (int p = 0; p < 4; p++)
        gload_lds16(gb + p*4096 + tid*16, lb + p*4096 + tid*16);
    }
    f32x4 acc[2] = {{0,0,0,0},{0,0,0,0}};
    for (int c = 0; c < 12; c++){
      int buf = c & 1;
      ushort_t* ad = &As[buf][arow][a4];
      ad[0]=f2bf(ra.x); ad[1]=f2bf(ra.y); ad[2]=f2bf(ra.z); ad[3]=f2bf(ra.w);
      __syncthreads();
      if (c < 11){
        ra = *(const float4*)(ap + (c+1)*64);
        const char* gb = (const char*)Msw + (size_t)(c+1)*16384;
        char* lb = (char*)&Bs[buf^1][0];
        #pragma unroll
        for (int p = 0; p < 4; p++)
          gload_lds16(gb + p*4096 + tid*16, lb + p*4096 + tid*16);
      }
      #pragma unroll
      for (int kcc = 0; kcc < 2; kcc++){
        short8 a = *(const short8*)&As[buf][m][kcc*32 + q*8];
        #pragma unroll
        for (int ct = 0; ct < 2; ct++){
          int col = wave*32 + ct*16 + m;
          short8 b = *(const short8*)&Bs[buf][(kcc*4 + q)*1024 + col*8];
          acc[ct] = __builtin_amdgcn_mfma_f32_16x16x32_bf16(a, b, acc[ct], 0, 0, 0);
        }
      }
    }
    #pragma unroll
    for (int ct = 0; ct < 2; ct++){
      int col = wave*32 + ct*16 + m;
      float kv = KV[col];
      #pragma unroll
      for (int r = 0; r < 4; r++)
        U[(size_t)(r0 + q*4 + r)*TR + col] = f2bf(acc[ct][r] + kv);
    }
  }
}

__global__ __launch_bounds__(256) void k3(const ushort_t* __restrict__ U, const ushort_t* __restrict__ Gt,
                                          const int* __restrict__ tgt, const int* __restrict__ perm,
                                          const ushort_t* __restrict__ W1b, const float* __restrict__ b1,
                                          const float* __restrict__ W2, const float* __restrict__ b2,
                                          float* __restrict__ out){
  __shared__ __align__(16) u64 bits_s8[16*10];
  __shared__ __align__(16) ushort_t h0s[32][136];
  __shared__ float sred[4][2][16][17];
  __shared__ float invs[16];
  __shared__ int   permS[16];

  int tid = threadIdx.x;
  int lane = tid & 63, wave = tid >> 6;
  int m = lane & 15, q = lane >> 4;
  int r0 = blockIdx.x * 16;

  if (tid < 16) permS[tid] = perm[r0 + tid];
  #pragma unroll
  for (int rr = 0; rr < 4; rr++){
    int row = wave*4 + rr;
    const int* rp = tgt + (size_t)(r0 + row)*LBL;
    int v[8];
    #pragma unroll
    for (int c = 0; c < 8; c++) v[c] = rp[c*64 + lane];
    int cnt = 0;
    #pragma unroll
    for (int c = 0; c < 8; c++){
      u64 mm = __ballot(v[c] != 0);
      if (lane == 0){ bits_s8[row*10 + c] = mm; cnt += __popcll(mm); }
    }
    if (lane == 0) invs[row] = 1.0f / (float)(cnt < 1 ? 1 : cnt);
  }
  __syncthreads();

  float up[2][4], un[2][4];
  #pragma unroll
  for (int ct = 0; ct < 2; ct++){
    int col = wave*32 + ct*16 + m;
    #pragma unroll
    for (int r = 0; r < 4; r++){
      int rowl = q*4 + r;
      up[ct][r] = bf2f(U[(size_t)(r0 + rowl)*TR + col]);
      un[ct][r] = bf2f(U[(size_t)permS[rowl]*TR + col]);
    }
  }

  const unsigned char* bits_b = (const unsigned char*)bits_s8;
  f32x4 accV[2] = {{0,0,0,0},{0,0,0,0}};
  const ushort_t* gp[2];
  #pragma unroll
  for (int ct = 0; ct < 2; ct++)
    gp[ct] = Gt + (size_t)(wave*32 + ct*16 + m)*LBL + q*8;
  short8 bcur[2], bnext[2];
  #pragma unroll
  for (int ct = 0; ct < 2; ct++) bcur[ct] = *(const short8*)(gp[ct]);
  int abase = m*80 + q;
  for (int c = 0; c < 16; c++){
    if (c < 15){
      #pragma unroll
      for (int ct = 0; ct < 2; ct++) bnext[ct] = *(const short8*)(gp[ct] + (c+1)*32);
    }
    unsigned bb = bits_b[abase + c*4];
    short8 a;
    #pragma unroll
    for (int j = 0; j < 8; j++) a[j] = (short)(((bb >> j) & 1u) ? 0x3F80 : 0);
    #pragma unroll
    for (int ct = 0; ct < 2; ct++)
      accV[ct] = __builtin_amdgcn_mfma_f32_16x16x32_bf16(a, bcur[ct], accV[ct], 0, 0, 0);
    #pragma unroll
    for (int ct = 0; ct < 2; ct++) bcur[ct] = bnext[ct];
  }

  #pragma unroll
  for (int ct = 0; ct < 2; ct++){
    int col = wave*32 + ct*16 + m;
    #pragma unroll
    for (int r = 0; r < 4; r++){
      int rowl = q*4 + r;
      float v = accV[ct][r] * invs[rowl];
      h0s[rowl][col]      = f2bf(fmaxf(up[ct][r] + v, 0.f));
      h0s[16 + rowl][col] = f2bf(fmaxf(un[ct][r] + v, 0.f));
    }
  }
  __syncthreads();

  float w2c[2], b1c[2];
  #pragma unroll
  for (int ct = 0; ct < 2; ct++){
    int col = wave*32 + ct*16 + m;
    w2c[ct] = W2[col];
    b1c[ct] = b1[col];
  }
  float b2v = b2[0];

  #pragma unroll
  for (int half = 0; half < 2; half++){
    f32x4 accH[2] = {{0,0,0,0},{0,0,0,0}};
    #pragma unroll
    for (int kc = 0; kc < 4; kc++){
      short8 a = *(const short8*)&h0s[half*16 + m][kc*32 + q*8];
      #pragma unroll
      for (int ct = 0; ct < 2; ct++){
        short8 b = *(const short8*)(W1b + (size_t)(wave*32 + ct*16 + m)*TR + kc*32 + q*8);
        accH[ct] = __builtin_amdgcn_mfma_f32_16x16x32_bf16(a, b, accH[ct], 0, 0, 0);
      }
    }
    #pragma unroll
    for (int r = 0; r < 4; r++){
      float sp = 0.f;
      #pragma unroll
      for (int ct = 0; ct < 2; ct++)
        sp = fmaf(w2c[ct], fmaxf(accH[ct][r] + b1c[ct], 0.f), sp);
      sred[wave][half][q*4 + r][m] = sp;
    }
  }
  __syncthreads();

  if (tid < 32){
    int half = tid >> 4, row = tid & 15;
    float s = b2v;
    #pragma unroll
    for (int wx = 0; wx < 4; wx++)
      #pragma unroll
      for (int n = 0; n < 16; n++) s += sred[wx][half][row][n];
    float val = half ? softplusf(s) : softplusf(-s);
    #pragma unroll
    for (int off = 16; off > 0; off >>= 1) val += __shfl_down(val, off);
    if (tid == 0) atomicAdd(out, val * (1.0f / (float)BATCH));
  }
}

extern "C" void kernel_launch(void* const* d_in, const int* in_sizes, int n_in,
                              void* d_out, int out_size, void* d_ws, size_t ws_size,
                              hipStream_t stream){
  const float* text = (const float*)d_in[0];
  const float* labe = (const float*)d_in[1];
  const int*   tgt  = (const int*)  d_in[2];
  const int*   perm = (const int*)  d_in[3];
  const float* Wt   = (const float*)d_in[4];
  const float* bt   = (const float*)d_in[5];
  const float* Wl   = (const float*)d_in[6];
  const float* bl   = (const float*)d_in[7];
  const float* W0   = (const float*)d_in[8];
  const float* b0   = (const float*)d_in[9];
  const float* W1   = (const float*)d_in[10];
  const float* b1   = (const float*)d_in[11];
  const float* W2   = (const float*)d_in[12];
  const float* b2   = (const float*)d_in[13];

  char* wsb = (char*)d_ws;
  size_t off = 0;
  auto alloc = [&](size_t bytes){
    size_t r = off;
    off += (bytes + 255) & ~(size_t)255;
    return r;
  };
  ushort_t* MSW = (ushort_t*)(wsb + alloc((size_t)TR*HID*2));
  ushort_t* QSW = (ushort_t*)(wsb + alloc((size_t)TR*HID*2));
  ushort_t* GT  = (ushort_t*)(wsb + alloc((size_t)TR*LBL*2));
  ushort_t* W1B = (ushort_t*)(wsb + alloc((size_t)TR*TR*2));
  float*    KV  = (float*)   (wsb + alloc((size_t)TR*4));
  ushort_t* U   = (ushort_t*)(wsb + alloc((size_t)BATCH*TR*2));
  float*    out = (float*)d_out;
  (void)ws_size; (void)in_sizes; (void)n_in; (void)out_size;

  // Guarded cooperative path: require >=2 resident blocks/CU (512-block grid on 256 CUs)
  int occ = 0;
  hipError_t qe = hipOccupancyMaxActiveBlocksPerMultiprocessor(&occ, (const void*)kfused, 256, 0);
  if (qe == hipSuccess && occ >= 2){
    void* args[] = {
      (void*)&W0, (void*)&Wt, (void*)&Wl, (void*)&bt, (void*)&bl, (void*)&b0,
      (void*)&W1, (void*)&text, (void*)&labe, (void*)&tgt, (void*)&perm,
      (void*)&b1, (void*)&W2, (void*)&b2,
      (void*)&MSW, (void*)&QSW, (void*)&W1B, (void*)&KV, (void*)&GT, (void*)&U,
      (void*)&out
    };
    hipError_t e = hipLaunchCooperativeKernel((const void*)kfused, dim3(512), dim3(256), args, 0, stream);
    if (e == hipSuccess) return;
  }

  // Fallback: proven 3-kernel pipeline
  k1<<<257, 256, 0, stream>>>(W0, Wt, Wl, bt, bl, b0, W1, MSW, QSW, W1B, KV, out);
  k2<<<1056, 256, 0, stream>>>(labe, QSW, text, MSW, KV, GT, U);
  k3<<<BATCH/16, 256, 0, stream>>>(U, GT, tgt, perm, W1B, b1, W2, b2, out);
}

// Round 9
// 175.768 us; speedup vs baseline: 2.3932x; 2.3932x over previous
//
#include <hip/hip_runtime.h>
#include <math.h>

#define BATCH 16384
#define LBL   512
#define HID   768
#define TR    128

typedef unsigned long long u64;
typedef unsigned short ushort_t;
typedef __attribute__((ext_vector_type(8))) short short8;
typedef __attribute__((ext_vector_type(4))) float f32x4;

__device__ __forceinline__ ushort_t f2bf(float f){
  unsigned u = __builtin_bit_cast(unsigned, f);
  u += 0x7FFFu + ((u >> 16) & 1u);
  return (ushort_t)(u >> 16);
}
__device__ __forceinline__ float bf2f(ushort_t h){
  unsigned u = ((unsigned)h) << 16;
  return __builtin_bit_cast(float, u);
}
__device__ __forceinline__ float softplusf(float x){
  return fmaxf(x, 0.0f) + log1pf(expf(-fabsf(x)));
}
__device__ __forceinline__ void gload_lds16(const void* g, void* l){
  __builtin_amdgcn_global_load_lds((const __attribute__((address_space(1))) void*)g,
                                   (__attribute__((address_space(3))) void*)l, 16, 0, 0);
}

// ============ k1: M = W0a@Wt, Q = W0b@Wl (swizzled bf16), W1->bf16, KV, zero out ============
// Swizzle: element (n, k) of a [128 n][768 k] B-matrix at ((k>>3)<<10) + (n<<3) + (k&7);
// chunk kc (64 k) = contiguous 16 KB at elem offset kc*8192 -> global_load_lds ready.
__global__ __launch_bounds__(256) void k1(
    const float* __restrict__ W0, const float* __restrict__ Wt, const float* __restrict__ Wl,
    const float* __restrict__ bt, const float* __restrict__ bl, const float* __restrict__ b0,
    const float* __restrict__ W1,
    ushort_t* __restrict__ Msw, ushort_t* __restrict__ Qsw, ushort_t* __restrict__ W1B,
    float* __restrict__ KV, float* __restrict__ out){
  __shared__ float sw[TR];
  int bi = blockIdx.x, t = threadIdx.x;
  if (bi < 256){
    int i = bi & 127;
    int isQ = bi >> 7;
    const float* src = isQ ? Wl : Wt;
    ushort_t* dst = isQ ? Qsw : Msw;
    if (t < TR) sw[t] = W0[(size_t)i*256 + isQ*128 + t];
    if (!isQ && t < 128) W1B[i*128 + t] = f2bf(W1[i*128 + t]);
    __syncthreads();
    int c = t;
    float a0 = 0.f, a1 = 0.f, a2 = 0.f;
    #pragma unroll 8
    for (int a = 0; a < 128; a++){
      float w = sw[a];
      const float* r = src + (size_t)a*HID;
      a0 = fmaf(w, r[c], a0);
      a1 = fmaf(w, r[c+256], a1);
      a2 = fmaf(w, r[c+512], a2);
    }
    int c7 = c & 7;
    dst[(((c      )>>3)<<10) + (i<<3) + c7] = f2bf(a0);
    dst[(((c + 256)>>3)<<10) + (i<<3) + c7] = f2bf(a1);
    dst[(((c + 512)>>3)<<10) + (i<<3) + c7] = f2bf(a2);
  } else {
    if (t < TR){
      float s = b0[t];
      const float* r = W0 + (size_t)t*256;
      for (int a = 0; a < 128; a++) s = fmaf(r[a], bt[a], s);
      for (int a = 0; a < 128; a++) s = fmaf(r[128+a], bl[a], s);
      KV[t] = s;
    }
    if (t == 0) out[0] = 0.f;
  }
}

// 32-row x 128-col tile GEMM, K=768. B pre-swizzled. A fp32 rows -> bf16 LDS.
// As_: [2][32][80] ushort (10240B); Bs_: [2][8192] ushort (32768B).
__device__ __forceinline__ void gemm768_32(const float* ap, const ushort_t* Bsw,
                                           ushort_t* As_, ushort_t* Bs_,
                                           int tid, int wave, int m, int q,
                                           f32x4 acc[2][2]){
  float4 ra0 = *(const float4*)ap;
  float4 ra1 = *(const float4*)(ap + 4);
  {
    const char* gb = (const char*)Bsw;
    char* lb = (char*)Bs_;
    #pragma unroll
    for (int p = 0; p < 4; p++)
      gload_lds16(gb + p*4096 + tid*16, lb + p*4096 + tid*16);
  }
  #pragma unroll
  for (int rt = 0; rt < 2; rt++)
    #pragma unroll
    for (int ct = 0; ct < 2; ct++)
      acc[rt][ct] = (f32x4){0.f,0.f,0.f,0.f};

  for (int c = 0; c < 12; c++){
    int buf = c & 1;
    short8 av;
    av[0] = (short)f2bf(ra0.x); av[1] = (short)f2bf(ra0.y);
    av[2] = (short)f2bf(ra0.z); av[3] = (short)f2bf(ra0.w);
    av[4] = (short)f2bf(ra1.x); av[5] = (short)f2bf(ra1.y);
    av[6] = (short)f2bf(ra1.z); av[7] = (short)f2bf(ra1.w);
    *(short8*)(As_ + (size_t)(buf*32 + (tid >> 3))*80 + (tid & 7)*8) = av;
    __syncthreads();
    if (c < 11){
      ra0 = *(const float4*)(ap + (c+1)*64);
      ra1 = *(const float4*)(ap + (c+1)*64 + 4);
      const char* gb = (const char*)Bsw + (size_t)(c+1)*16384;
      char* lb = (char*)(Bs_ + (buf^1)*8192);
      #pragma unroll
      for (int p = 0; p < 4; p++)
        gload_lds16(gb + p*4096 + tid*16, lb + p*4096 + tid*16);
    }
    #pragma unroll
    for (int kcc = 0; kcc < 2; kcc++){
      short8 bfr[2];
      #pragma unroll
      for (int ct = 0; ct < 2; ct++)
        bfr[ct] = *(const short8*)(Bs_ + buf*8192 + (kcc*4 + q)*1024 + (wave*32 + ct*16 + m)*8);
      #pragma unroll
      for (int rt = 0; rt < 2; rt++){
        short8 a = *(const short8*)(As_ + (size_t)(buf*32 + rt*16 + m)*80 + kcc*32 + q*8);
        #pragma unroll
        for (int ct = 0; ct < 2; ct++)
          acc[rt][ct] = __builtin_amdgcn_mfma_f32_16x16x32_bf16(a, bfr[ct], acc[rt][ct], 0, 0, 0);
      }
    }
  }
}

// ============ k2: bitpack (0..511) | G-GEMM (512..527) | U-GEMM (528..1039) ============
__global__ __launch_bounds__(256) void k2(
    const float* __restrict__ labe, const ushort_t* __restrict__ Qsw,
    const float* __restrict__ T,    const ushort_t* __restrict__ Msw,
    const float* __restrict__ KV,   const int* __restrict__ tgt,
    ushort_t* __restrict__ Gt, ushort_t* __restrict__ U,
    u64* __restrict__ bits, float* __restrict__ inv){
  __shared__ __align__(16) char uni[43008];   // Bs [2][8192] ushort + As [2][32][80] ushort
  int bi = blockIdx.x, tid = threadIdx.x;
  int lane = tid & 63, wave = tid >> 6;
  int m = lane & 15, q = lane >> 4;
  int arow = tid >> 3, ak = (tid & 7) * 8;
  ushort_t* Bs_ = (ushort_t*)uni;
  ushort_t* As_ = (ushort_t*)(uni + 32768);

  if (bi < 512){
    // ---- bitpack 32 target rows: wave handles 8 rows ----
    int b0r = bi*32;
    #pragma unroll
    for (int rr = 0; rr < 8; rr++){
      int row = b0r + wave*8 + rr;
      const int* rp = tgt + (size_t)row*LBL;
      int v[8];
      #pragma unroll
      for (int c = 0; c < 8; c++) v[c] = rp[c*64 + lane];
      int cnt = 0;
      #pragma unroll
      for (int c = 0; c < 8; c++){
        u64 mm = __ballot(v[c] != 0);
        if (lane == 0){ bits[(size_t)row*8 + c] = mm; cnt += __popcll(mm); }
      }
      if (lane == 0) inv[row] = 1.0f / (float)(cnt < 1 ? 1 : cnt);
    }
  } else if (bi < 528){
    // ---- G = labe @ Q^T, 32 labels ----
    int l0 = (bi - 512) * 32;
    f32x4 accG[2][2];
    gemm768_32(labe + (size_t)(l0 + arow)*HID + ak, Qsw, As_, Bs_, tid, wave, m, q, accG);
    __syncthreads();
    ushort_t (*GTs)[40] = (ushort_t(*)[40])uni;   // [128][40]
    #pragma unroll
    for (int rt = 0; rt < 2; rt++)
      #pragma unroll
      for (int ct = 0; ct < 2; ct++){
        int col = wave*32 + ct*16 + m;
        #pragma unroll
        for (int r = 0; r < 4; r++)
          GTs[col][rt*16 + q*4 + r] = f2bf(accG[rt][ct][r]);
      }
    __syncthreads();
    int gi = tid >> 1, half = tid & 1;
    ushort_t* dstp = Gt + (size_t)gi*LBL + l0 + half*16;
    *(short8*)(dstp)     = *(const short8*)&GTs[gi][half*16];
    *(short8*)(dstp + 8) = *(const short8*)&GTs[gi][half*16 + 8];
  } else {
    // ---- U = text @ M^T + KV, 32 rows ----
    int r0 = (bi - 528) * 32;
    f32x4 accU[2][2];
    gemm768_32(T + (size_t)(r0 + arow)*HID + ak, Msw, As_, Bs_, tid, wave, m, q, accU);
    #pragma unroll
    for (int rt = 0; rt < 2; rt++)
      #pragma unroll
      for (int ct = 0; ct < 2; ct++){
        int col = wave*32 + ct*16 + m;
        float kv = KV[col];
        #pragma unroll
        for (int r = 0; r < 4; r++)
          U[(size_t)(r0 + rt*16 + q*4 + r)*TR + col] = f2bf(accU[rt][ct][r] + kv);
      }
  }
}

// ============ k3: V + h0(both) + h1(both) + score -> scaled atomic.  512 blocks x 32 rows ============
__global__ __launch_bounds__(256) void k3(const ushort_t* __restrict__ U, const ushort_t* __restrict__ Gt,
                                          const u64* __restrict__ BITS_, const float* __restrict__ INV,
                                          const int* __restrict__ perm, const ushort_t* __restrict__ W1b,
                                          const float* __restrict__ b1, const float* __restrict__ W2,
                                          const float* __restrict__ b2, float* __restrict__ out){
  __shared__ __align__(16) u64 bitsS[32*10];        // 80B pitch per row
  __shared__ __align__(16) ushort_t h0s[64][136];   // 0-31 pos, 32-63 neg
  __shared__ float sred[4*4*16*17];                 // [wave][rt2][row16][17]
  __shared__ float invs[32];
  __shared__ int   permS[32];

  int tid = threadIdx.x;
  int lane = tid & 63, wave = tid >> 6;
  int m = lane & 15, q = lane >> 4;
  int r0 = blockIdx.x * 32;

  if (tid < 128){
    int row = tid >> 2, seg = tid & 3;
    const int4* src = (const int4*)((const char*)BITS_ + (size_t)(r0+row)*64 + seg*16);
    *(int4*)((char*)bitsS + row*80 + seg*16) = *src;
  } else if (tid < 160){
    invs[tid & 31] = INV[r0 + (tid & 31)];
  } else if (tid < 192){
    permS[tid & 31] = perm[r0 + (tid & 31)];
  }
  __syncthreads();

  // hoist U loads (latency covered by V-GEMM)
  float up[2][2][4], un[2][2][4];
  #pragma unroll
  for (int rt = 0; rt < 2; rt++)
    #pragma unroll
    for (int ct = 0; ct < 2; ct++){
      int col = wave*32 + ct*16 + m;
      #pragma unroll
      for (int r = 0; r < 4; r++){
        int rowl = rt*16 + q*4 + r;
        up[rt][ct][r] = bf2f(U[(size_t)(r0 + rowl)*TR + col]);
        un[rt][ct][r] = bf2f(U[(size_t)permS[rowl]*TR + col]);
      }
    }

  // V = mask @ G (K=512), Gt prefetch 1-deep
  const unsigned char* bits_b = (const unsigned char*)bitsS;
  f32x4 accV[2][2] = {{{0,0,0,0},{0,0,0,0}},{{0,0,0,0},{0,0,0,0}}};
  const ushort_t* gp[2];
  #pragma unroll
  for (int ct = 0; ct < 2; ct++)
    gp[ct] = Gt + (size_t)(wave*32 + ct*16 + m)*LBL + q*8;
  short8 bcur[2], bnext[2];
  #pragma unroll
  for (int ct = 0; ct < 2; ct++) bcur[ct] = *(const short8*)(gp[ct]);
  for (int c = 0; c < 16; c++){
    if (c < 15){
      #pragma unroll
      for (int ct = 0; ct < 2; ct++) bnext[ct] = *(const short8*)(gp[ct] + (c+1)*32);
    }
    #pragma unroll
    for (int rt = 0; rt < 2; rt++){
      unsigned bb = bits_b[(rt*16 + m)*80 + c*4 + q];
      short8 a;
      #pragma unroll
      for (int j = 0; j < 8; j++) a[j] = (short)(((bb >> j) & 1u) ? 0x3F80 : 0);
      #pragma unroll
      for (int ct = 0; ct < 2; ct++)
        accV[rt][ct] = __builtin_amdgcn_mfma_f32_16x16x32_bf16(a, bcur[ct], accV[rt][ct], 0, 0, 0);
    }
    #pragma unroll
    for (int ct = 0; ct < 2; ct++) bcur[ct] = bnext[ct];
  }

  // h0 both branches -> LDS
  #pragma unroll
  for (int rt = 0; rt < 2; rt++)
    #pragma unroll
    for (int ct = 0; ct < 2; ct++){
      int col = wave*32 + ct*16 + m;
      #pragma unroll
      for (int r = 0; r < 4; r++){
        int rowl = rt*16 + q*4 + r;
        float v = accV[rt][ct][r] * invs[rowl];
        h0s[rowl][col]      = f2bf(fmaxf(up[rt][ct][r] + v, 0.f));
        h0s[32 + rowl][col] = f2bf(fmaxf(un[rt][ct][r] + v, 0.f));
      }
    }
  __syncthreads();

  float w2c[2], b1c[2];
  #pragma unroll
  for (int ct = 0; ct < 2; ct++){
    int col = wave*32 + ct*16 + m;
    w2c[ct] = W2[col];
    b1c[ct] = b1[col];
  }
  float b2v = b2[0];

  #pragma unroll
  for (int rt2 = 0; rt2 < 4; rt2++){
    f32x4 accH[2] = {{0,0,0,0},{0,0,0,0}};
    #pragma unroll
    for (int kc = 0; kc < 4; kc++){
      short8 a = *(const short8*)&h0s[rt2*16 + m][kc*32 + q*8];
      #pragma unroll
      for (int ct = 0; ct < 2; ct++){
        short8 b = *(const short8*)(W1b + (size_t)(wave*32 + ct*16 + m)*TR + kc*32 + q*8);
        accH[ct] = __builtin_amdgcn_mfma_f32_16x16x32_bf16(a, b, accH[ct], 0, 0, 0);
      }
    }
    #pragma unroll
    for (int r = 0; r < 4; r++){
      float sp = 0.f;
      #pragma unroll
      for (int ct = 0; ct < 2; ct++)
        sp = fmaf(w2c[ct], fmaxf(accH[ct][r] + b1c[ct], 0.f), sp);
      sred[((wave*4 + rt2)*16 + q*4 + r)*17 + m] = sp;
    }
  }
  __syncthreads();

  if (tid < 64){
    int rt2 = tid >> 4, row = tid & 15;
    float s = b2v;
    #pragma unroll
    for (int wx = 0; wx < 4; wx++)
      #pragma unroll
      for (int n = 0; n < 16; n++) s += sred[((wx*4 + rt2)*16 + row)*17 + n];
    float val = (rt2 < 2) ? softplusf(-s) : softplusf(s);   // rt2 0,1 = pos branch
    #pragma unroll
    for (int off = 32; off > 0; off >>= 1) val += __shfl_down(val, off);
    if (tid == 0) atomicAdd(out, val * (1.0f / (float)BATCH));
  }
}

extern "C" void kernel_launch(void* const* d_in, const int* in_sizes, int n_in,
                              void* d_out, int out_size, void* d_ws, size_t ws_size,
                              hipStream_t stream){
  const float* text = (const float*)d_in[0];
  const float* labe = (const float*)d_in[1];
  const int*   tgt  = (const int*)  d_in[2];
  const int*   perm = (const int*)  d_in[3];
  const float* Wt   = (const float*)d_in[4];
  const float* bt   = (const float*)d_in[5];
  const float* Wl   = (const float*)d_in[6];
  const float* bl   = (const float*)d_in[7];
  const float* W0   = (const float*)d_in[8];
  const float* b0   = (const float*)d_in[9];
  const float* W1   = (const float*)d_in[10];
  const float* b1   = (const float*)d_in[11];
  const float* W2   = (const float*)d_in[12];
  const float* b2   = (const float*)d_in[13];

  char* wsb = (char*)d_ws;
  size_t off = 0;
  auto alloc = [&](size_t bytes){
    size_t r = off;
    off += (bytes + 255) & ~(size_t)255;
    return r;
  };
  ushort_t* MSW = (ushort_t*)(wsb + alloc((size_t)TR*HID*2));
  ushort_t* QSW = (ushort_t*)(wsb + alloc((size_t)TR*HID*2));
  ushort_t* GT  = (ushort_t*)(wsb + alloc((size_t)TR*LBL*2));
  ushort_t* W1B = (ushort_t*)(wsb + alloc((size_t)TR*TR*2));
  float*    KV  = (float*)   (wsb + alloc((size_t)TR*4));
  u64*      BITS= (u64*)     (wsb + alloc((size_t)BATCH*8*8));
  float*    INV = (float*)   (wsb + alloc((size_t)BATCH*4));
  ushort_t* U   = (ushort_t*)(wsb + alloc((size_t)BATCH*TR*2));
  float*    out = (float*)d_out;
  (void)ws_size; (void)in_sizes; (void)n_in; (void)out_size;

  k1<<<257, 256, 0, stream>>>(W0, Wt, Wl, bt, bl, b0, W1, MSW, QSW, W1B, KV, out);
  k2<<<1040, 256, 0, stream>>>(labe, QSW, text, MSW, KV, tgt, GT, U, BITS, INV);
  k3<<<512, 256, 0, stream>>>(U, GT, BITS, INV, perm, W1B, b1, W2, b2, out);
}

// Round 10
// 171.645 us; speedup vs baseline: 2.4506x; 1.0240x over previous
//
#include <hip/hip_runtime.h>
#include <math.h>

#define BATCH 16384
#define LBL   512
#define HID   768
#define TR    128

typedef unsigned long long u64;
typedef unsigned short ushort_t;
typedef __attribute__((ext_vector_type(8))) short short8;
typedef __attribute__((ext_vector_type(4))) float f32x4;

__device__ __forceinline__ ushort_t f2bf(float f){
  unsigned u = __builtin_bit_cast(unsigned, f);
  u += 0x7FFFu + ((u >> 16) & 1u);
  return (ushort_t)(u >> 16);
}
__device__ __forceinline__ float softplusf(float x){
  return fmaxf(x, 0.0f) + log1pf(expf(-fabsf(x)));
}
__device__ __forceinline__ void gload_lds16(const void* g, void* l){
  __builtin_amdgcn_global_load_lds((const __attribute__((address_space(1))) void*)g,
                                   (__attribute__((address_space(3))) void*)l, 16, 0, 0);
}

// ============ k1: M = W0a@Wt, Q = W0b@Wl (swizzled bf16), W1->bf16, KV, zero out ============
// Swizzle: element (n, k) of a [128 n][768 k] B-matrix at ((k>>3)<<10) + (n<<3) + (k&7);
// chunk kc (64 k) = contiguous 16 KB at elem offset kc*8192 -> global_load_lds ready.
__global__ __launch_bounds__(256) void k1(
    const float* __restrict__ W0, const float* __restrict__ Wt, const float* __restrict__ Wl,
    const float* __restrict__ bt, const float* __restrict__ bl, const float* __restrict__ b0,
    const float* __restrict__ W1,
    ushort_t* __restrict__ Msw, ushort_t* __restrict__ Qsw, ushort_t* __restrict__ W1B,
    float* __restrict__ KV, float* __restrict__ out){
  __shared__ float sw[TR];
  int bi = blockIdx.x, t = threadIdx.x;
  if (bi < 256){
    int i = bi & 127;
    int isQ = bi >> 7;
    const float* src = isQ ? Wl : Wt;
    ushort_t* dst = isQ ? Qsw : Msw;
    if (t < TR) sw[t] = W0[(size_t)i*256 + isQ*128 + t];
    if (!isQ && t < 128) W1B[i*128 + t] = f2bf(W1[i*128 + t]);
    __syncthreads();
    int c = t;
    float a0 = 0.f, a1 = 0.f, a2 = 0.f;
    #pragma unroll 8
    for (int a = 0; a < 128; a++){
      float w = sw[a];
      const float* r = src + (size_t)a*HID;
      a0 = fmaf(w, r[c], a0);
      a1 = fmaf(w, r[c+256], a1);
      a2 = fmaf(w, r[c+512], a2);
    }
    int c7 = c & 7;
    dst[(((c      )>>3)<<10) + (i<<3) + c7] = f2bf(a0);
    dst[(((c + 256)>>3)<<10) + (i<<3) + c7] = f2bf(a1);
    dst[(((c + 512)>>3)<<10) + (i<<3) + c7] = f2bf(a2);
  } else {
    if (t < TR){
      float s = b0[t];
      const float* r = W0 + (size_t)t*256;
      for (int a = 0; a < 128; a++) s = fmaf(r[a], bt[a], s);
      for (int a = 0; a < 128; a++) s = fmaf(r[128+a], bl[a], s);
      KV[t] = s;
    }
    if (t == 0) out[0] = 0.f;
  }
}

// 32-row x 128-col tile GEMM, K=768. B pre-swizzled. A fp32 rows -> bf16 LDS.
// As_: [2][32][80] ushort; Bs_: [2][8192] ushort.
__device__ __forceinline__ void gemm768_32(const float* ap, const ushort_t* Bsw,
                                           ushort_t* As_, ushort_t* Bs_,
                                           int tid, int wave, int m, int q,
                                           f32x4 acc[2][2]){
  float4 ra0 = *(const float4*)ap;
  float4 ra1 = *(const float4*)(ap + 4);
  {
    const char* gb = (const char*)Bsw;
    char* lb = (char*)Bs_;
    #pragma unroll
    for (int p = 0; p < 4; p++)
      gload_lds16(gb + p*4096 + tid*16, lb + p*4096 + tid*16);
  }
  #pragma unroll
  for (int rt = 0; rt < 2; rt++)
    #pragma unroll
    for (int ct = 0; ct < 2; ct++)
      acc[rt][ct] = (f32x4){0.f,0.f,0.f,0.f};

  for (int c = 0; c < 12; c++){
    int buf = c & 1;
    short8 av;
    av[0] = (short)f2bf(ra0.x); av[1] = (short)f2bf(ra0.y);
    av[2] = (short)f2bf(ra0.z); av[3] = (short)f2bf(ra0.w);
    av[4] = (short)f2bf(ra1.x); av[5] = (short)f2bf(ra1.y);
    av[6] = (short)f2bf(ra1.z); av[7] = (short)f2bf(ra1.w);
    *(short8*)(As_ + (size_t)(buf*32 + (tid >> 3))*80 + (tid & 7)*8) = av;
    __syncthreads();
    if (c < 11){
      ra0 = *(const float4*)(ap + (c+1)*64);
      ra1 = *(const float4*)(ap + (c+1)*64 + 4);
      const char* gb = (const char*)Bsw + (size_t)(c+1)*16384;
      char* lb = (char*)(Bs_ + (buf^1)*8192);
      #pragma unroll
      for (int p = 0; p < 4; p++)
        gload_lds16(gb + p*4096 + tid*16, lb + p*4096 + tid*16);
    }
    #pragma unroll
    for (int kcc = 0; kcc < 2; kcc++){
      short8 bfr[2];
      #pragma unroll
      for (int ct = 0; ct < 2; ct++)
        bfr[ct] = *(const short8*)(Bs_ + buf*8192 + (kcc*4 + q)*1024 + (wave*32 + ct*16 + m)*8);
      #pragma unroll
      for (int rt = 0; rt < 2; rt++){
        short8 a = *(const short8*)(As_ + (size_t)(buf*32 + rt*16 + m)*80 + kcc*32 + q*8);
        #pragma unroll
        for (int ct = 0; ct < 2; ct++)
          acc[rt][ct] = __builtin_amdgcn_mfma_f32_16x16x32_bf16(a, bfr[ct], acc[rt][ct], 0, 0, 0);
      }
    }
  }
}

// ============ k2: G-GEMM (0..15) | bitpack (16..527) ============
__global__ __launch_bounds__(256) void k2(
    const float* __restrict__ labe, const ushort_t* __restrict__ Qsw,
    const int* __restrict__ tgt,
    ushort_t* __restrict__ Gt, u64* __restrict__ bits, float* __restrict__ inv){
  __shared__ __align__(16) char uni[43008];
  int bi = blockIdx.x, tid = threadIdx.x;
  int lane = tid & 63, wave = tid >> 6;
  int m = lane & 15, q = lane >> 4;
  ushort_t* Bs_ = (ushort_t*)uni;
  ushort_t* As_ = (ushort_t*)(uni + 32768);

  if (bi < 16){
    // ---- G = labe @ Q^T, 32 labels ----
    int l0 = bi * 32;
    int arow = tid >> 3, ak = (tid & 7) * 8;
    f32x4 accG[2][2];
    gemm768_32(labe + (size_t)(l0 + arow)*HID + ak, Qsw, As_, Bs_, tid, wave, m, q, accG);
    __syncthreads();
    ushort_t (*GTs)[40] = (ushort_t(*)[40])uni;   // [128][40]
    #pragma unroll
    for (int rt = 0; rt < 2; rt++)
      #pragma unroll
      for (int ct = 0; ct < 2; ct++){
        int col = wave*32 + ct*16 + m;
        #pragma unroll
        for (int r = 0; r < 4; r++)
          GTs[col][rt*16 + q*4 + r] = f2bf(accG[rt][ct][r]);
      }
    __syncthreads();
    int gi = tid >> 1, half = tid & 1;
    ushort_t* dstp = Gt + (size_t)gi*LBL + l0 + half*16;
    *(short8*)(dstp)     = *(const short8*)&GTs[gi][half*16];
    *(short8*)(dstp + 8) = *(const short8*)&GTs[gi][half*16 + 8];
  } else {
    // ---- bitpack 32 target rows: wave handles 8 rows ----
    int b0r = (bi - 16)*32;
    #pragma unroll
    for (int rr = 0; rr < 8; rr++){
      int row = b0r + wave*8 + rr;
      const int* rp = tgt + (size_t)row*LBL;
      int v[8];
      #pragma unroll
      for (int c = 0; c < 8; c++) v[c] = rp[c*64 + lane];
      int cnt = 0;
      #pragma unroll
      for (int c = 0; c < 8; c++){
        u64 mm = __ballot(v[c] != 0);
        if (lane == 0){ bits[(size_t)row*8 + c] = mm; cnt += __popcll(mm); }
      }
      if (lane == 0) inv[row] = 1.0f / (float)(cnt < 1 ? 1 : cnt);
    }
  }
}

// ============ k3: 64-row U-GEMM (32 pos + 32 perm-gathered neg) + V + h0 + h1 + score ============
// 512 blocks x 256 thr, 32 samples/block. No U materialization.
// LDS: uni 51200 (Bs 32768 + As [2][64][72] 18432; phase-C overlay h0s 17408 + sred 17408)
//      + bitsS 2560 + invs 128 = 53888 B -> 3 blocks/CU.
__global__ __launch_bounds__(256) void k3(const float* __restrict__ T, const ushort_t* __restrict__ Msw,
                                          const float* __restrict__ KV, const ushort_t* __restrict__ Gt,
                                          const u64* __restrict__ BITS_, const float* __restrict__ INV,
                                          const int* __restrict__ perm, const ushort_t* __restrict__ W1b,
                                          const float* __restrict__ b1, const float* __restrict__ W2,
                                          const float* __restrict__ b2, float* __restrict__ out){
  __shared__ __align__(16) char uni[51200];
  __shared__ __align__(16) u64 bitsS[32*10];   // 80B pitch
  __shared__ float invs[32];

  int tid = threadIdx.x;
  int lane = tid & 63, wave = tid >> 6;
  int m = lane & 15, q = lane >> 4;
  int r0 = blockIdx.x * 32;
  ushort_t* Bs_ = (ushort_t*)uni;              // [2][8192]
  ushort_t* As_ = (ushort_t*)(uni + 32768);    // [2][64][72]

  // stage bits + inv
  if (tid < 128){
    int row = tid >> 2, seg = tid & 3;
    const int4* src = (const int4*)((const char*)BITS_ + (size_t)(r0+row)*64 + seg*16);
    *(int4*)((char*)bitsS + row*80 + seg*16) = *src;
  } else if (tid < 160){
    invs[tid & 31] = INV[r0 + (tid & 31)];
  }

  // ---- 64-row GEMM: rows 0..31 = text[r0+i], rows 32..63 = text[perm[r0+i]] ----
  int ar = tid >> 3, ak = (tid & 7) * 8;
  const float* app = T + (size_t)(r0 + ar)*HID + ak;
  int pg = perm[r0 + ar];
  const float* apn = T + (size_t)pg*HID + ak;

  float4 pa0 = *(const float4*)(app);
  float4 pa1 = *(const float4*)(app + 4);
  float4 na0 = *(const float4*)(apn);
  float4 na1 = *(const float4*)(apn + 4);
  {
    const char* gb = (const char*)Msw;
    char* lb = (char*)Bs_;
    #pragma unroll
    for (int p = 0; p < 4; p++)
      gload_lds16(gb + p*4096 + tid*16, lb + p*4096 + tid*16);
  }
  f32x4 acc[4][2];
  #pragma unroll
  for (int rt = 0; rt < 4; rt++)
    #pragma unroll
    for (int ct = 0; ct < 2; ct++)
      acc[rt][ct] = (f32x4){0.f,0.f,0.f,0.f};

  for (int c = 0; c < 12; c++){
    int buf = c & 1;
    short8 pv, nv;
    pv[0]=(short)f2bf(pa0.x); pv[1]=(short)f2bf(pa0.y); pv[2]=(short)f2bf(pa0.z); pv[3]=(short)f2bf(pa0.w);
    pv[4]=(short)f2bf(pa1.x); pv[5]=(short)f2bf(pa1.y); pv[6]=(short)f2bf(pa1.z); pv[7]=(short)f2bf(pa1.w);
    nv[0]=(short)f2bf(na0.x); nv[1]=(short)f2bf(na0.y); nv[2]=(short)f2bf(na0.z); nv[3]=(short)f2bf(na0.w);
    nv[4]=(short)f2bf(na1.x); nv[5]=(short)f2bf(na1.y); nv[6]=(short)f2bf(na1.z); nv[7]=(short)f2bf(na1.w);
    *(short8*)(As_ + (size_t)(buf*64 + ar)*72 + ak)      = pv;
    *(short8*)(As_ + (size_t)(buf*64 + 32 + ar)*72 + ak) = nv;
    __syncthreads();
    if (c < 11){
      pa0 = *(const float4*)(app + (c+1)*64);
      pa1 = *(const float4*)(app + (c+1)*64 + 4);
      na0 = *(const float4*)(apn + (c+1)*64);
      na1 = *(const float4*)(apn + (c+1)*64 + 4);
      const char* gb = (const char*)Msw + (size_t)(c+1)*16384;
      char* lb = (char*)(Bs_ + (buf^1)*8192);
      #pragma unroll
      for (int p = 0; p < 4; p++)
        gload_lds16(gb + p*4096 + tid*16, lb + p*4096 + tid*16);
    }
    #pragma unroll
    for (int kcc = 0; kcc < 2; kcc++){
      short8 bfr[2];
      #pragma unroll
      for (int ct = 0; ct < 2; ct++)
        bfr[ct] = *(const short8*)(Bs_ + buf*8192 + (kcc*4 + q)*1024 + (wave*32 + ct*16 + m)*8);
      #pragma unroll
      for (int rt = 0; rt < 4; rt++){
        short8 a = *(const short8*)(As_ + (size_t)(buf*64 + rt*16 + m)*72 + kcc*32 + q*8);
        #pragma unroll
        for (int ct = 0; ct < 2; ct++)
          acc[rt][ct] = __builtin_amdgcn_mfma_f32_16x16x32_bf16(a, bfr[ct], acc[rt][ct], 0, 0, 0);
      }
    }
  }

  // ---- V = mask @ G (K=512), Gt prefetch 1-deep ----
  const unsigned char* bits_b = (const unsigned char*)bitsS;
  f32x4 accV[2][2] = {{{0,0,0,0},{0,0,0,0}},{{0,0,0,0},{0,0,0,0}}};
  const ushort_t* gp[2];
  #pragma unroll
  for (int ct = 0; ct < 2; ct++)
    gp[ct] = Gt + (size_t)(wave*32 + ct*16 + m)*LBL + q*8;
  short8 bcur[2], bnext[2];
  #pragma unroll
  for (int ct = 0; ct < 2; ct++) bcur[ct] = *(const short8*)(gp[ct]);
  for (int c = 0; c < 16; c++){
    if (c < 15){
      #pragma unroll
      for (int ct = 0; ct < 2; ct++) bnext[ct] = *(const short8*)(gp[ct] + (c+1)*32);
    }
    #pragma unroll
    for (int rt = 0; rt < 2; rt++){
      unsigned bb = bits_b[(rt*16 + m)*80 + c*4 + q];
      short8 a;
      #pragma unroll
      for (int j = 0; j < 8; j++) a[j] = (short)(((bb >> j) & 1u) ? 0x3F80 : 0);
      #pragma unroll
      for (int ct = 0; ct < 2; ct++)
        accV[rt][ct] = __builtin_amdgcn_mfma_f32_16x16x32_bf16(a, bcur[ct], accV[rt][ct], 0, 0, 0);
    }
    #pragma unroll
    for (int ct = 0; ct < 2; ct++) bcur[ct] = bnext[ct];
  }

  // ---- h0 both branches -> LDS (overlay on uni; GEMM LDS dead now) ----
  __syncthreads();
  ushort_t (*h0s)[136] = (ushort_t(*)[136])uni;   // [64][136]: 0-31 pos, 32-63 neg
  float* sred = (float*)(uni + 17408);            // [4][4][16][17]
  #pragma unroll
  for (int rt = 0; rt < 2; rt++)
    #pragma unroll
    for (int ct = 0; ct < 2; ct++){
      int col = wave*32 + ct*16 + m;
      float kv = KV[col];
      #pragma unroll
      for (int r = 0; r < 4; r++){
        int rowl = rt*16 + q*4 + r;
        float v = accV[rt][ct][r] * invs[rowl] + kv;
        h0s[rowl][col]      = f2bf(fmaxf(acc[rt][ct][r]   + v, 0.f));
        h0s[32 + rowl][col] = f2bf(fmaxf(acc[rt+2][ct][r] + v, 0.f));
      }
    }
  __syncthreads();

  float w2c[2], b1c[2];
  #pragma unroll
  for (int ct = 0; ct < 2; ct++){
    int col = wave*32 + ct*16 + m;
    w2c[ct] = W2[col];
    b1c[ct] = b1[col];
  }
  float b2v = b2[0];

  #pragma unroll
  for (int rt2 = 0; rt2 < 4; rt2++){
    f32x4 accH[2] = {{0,0,0,0},{0,0,0,0}};
    #pragma unroll
    for (int kc = 0; kc < 4; kc++){
      short8 a = *(const short8*)&h0s[rt2*16 + m][kc*32 + q*8];
      #pragma unroll
      for (int ct = 0; ct < 2; ct++){
        short8 b = *(const short8*)(W1b + (size_t)(wave*32 + ct*16 + m)*TR + kc*32 + q*8);
        accH[ct] = __builtin_amdgcn_mfma_f32_16x16x32_bf16(a, b, accH[ct], 0, 0, 0);
      }
    }
    #pragma unroll
    for (int r = 0; r < 4; r++){
      float sp = 0.f;
      #pragma unroll
      for (int ct = 0; ct < 2; ct++)
        sp = fmaf(w2c[ct], fmaxf(accH[ct][r] + b1c[ct], 0.f), sp);
      sred[((wave*4 + rt2)*16 + q*4 + r)*17 + m] = sp;
    }
  }
  __syncthreads();

  if (tid < 64){
    int rt2 = tid >> 4, row = tid & 15;
    float s = b2v;
    #pragma unroll
    for (int wx = 0; wx < 4; wx++)
      #pragma unroll
      for (int n = 0; n < 16; n++) s += sred[((wx*4 + rt2)*16 + row)*17 + n];
    float val = (rt2 < 2) ? softplusf(-s) : softplusf(s);   // rt2 0,1 = pos branch
    #pragma unroll
    for (int off = 32; off > 0; off >>= 1) val += __shfl_down(val, off);
    if (tid == 0) atomicAdd(out, val * (1.0f / (float)BATCH));
  }
}

extern "C" void kernel_launch(void* const* d_in, const int* in_sizes, int n_in,
                              void* d_out, int out_size, void* d_ws, size_t ws_size,
                              hipStream_t stream){
  const float* text = (const float*)d_in[0];
  const float* labe = (const float*)d_in[1];
  const int*   tgt  = (const int*)  d_in[2];
  const int*   perm = (const int*)  d_in[3];
  const float* Wt   = (const float*)d_in[4];
  const float* bt   = (const float*)d_in[5];
  const float* Wl   = (const float*)d_in[6];
  const float* bl   = (const float*)d_in[7];
  const float* W0   = (const float*)d_in[8];
  const float* b0   = (const float*)d_in[9];
  const float* W1   = (const float*)d_in[10];
  const float* b1   = (const float*)d_in[11];
  const float* W2   = (const float*)d_in[12];
  const float* b2   = (const float*)d_in[13];

  char* wsb = (char*)d_ws;
  size_t off = 0;
  auto alloc = [&](size_t bytes){
    size_t r = off;
    off += (bytes + 255) & ~(size_t)255;
    return r;
  };
  ushort_t* MSW = (ushort_t*)(wsb + alloc((size_t)TR*HID*2));
  ushort_t* QSW = (ushort_t*)(wsb + alloc((size_t)TR*HID*2));
  ushort_t* GT  = (ushort_t*)(wsb + alloc((size_t)TR*LBL*2));
  ushort_t* W1B = (ushort_t*)(wsb + alloc((size_t)TR*TR*2));
  float*    KV  = (float*)   (wsb + alloc((size_t)TR*4));
  u64*      BITS= (u64*)     (wsb + alloc((size_t)BATCH*8*8));
  float*    INV = (float*)   (wsb + alloc((size_t)BATCH*4));
  float*    out = (float*)d_out;
  (void)ws_size; (void)in_sizes; (void)n_in; (void)out_size;

  k1<<<257, 256, 0, stream>>>(W0, Wt, Wl, bt, bl, b0, W1, MSW, QSW, W1B, KV, out);
  k2<<<528, 256, 0, stream>>>(labe, QSW, tgt, GT, BITS, INV);
  k3<<<512, 256, 0, stream>>>(text, MSW, KV, GT, BITS, INV, perm, W1B, b1, W2, b2, out);
}